// Round 7
// baseline (1571.270 us; speedup 1.0000x reference)
//
#include <hip/hip_runtime.h>
#include <hip/hip_bf16.h>
#include <math.h>

#define HEADS 4
#define HID 48
#define FDIM 192   // HEADS*HID
#define NEG_SLOPE 0.2f

typedef float f4 __attribute__((ext_vector_type(4)));

// ---------------------------------------------------------------------------
// DPP helpers (VALU-pipe cross-lane).
template<int CTRL>
__device__ __forceinline__ float dpp_add(float v) {
    int t = __builtin_amdgcn_update_dpp(0, __float_as_int(v), CTRL, 0xF, 0xF, true);
    return v + __int_as_float(t);
}
template<int CTRL>
__device__ __forceinline__ float dpp_max(float v) {
    int t = __builtin_amdgcn_update_dpp(0, __float_as_int(v), CTRL, 0xF, 0xF, true);
    return fmaxf(v, __int_as_float(t));
}
// sum over the 4 lanes of a quad (cq axis): quad_perm xor1 + xor2
__device__ __forceinline__ float red_cq(float v) {
    v = dpp_add<0xB1>(v);
    v = dpp_add<0x4E>(v);
    return v;
}
// max over a 16-lane row
__device__ __forceinline__ float rowmax16(float v) {
    v = dpp_max<0x124>(v);
    v = dpp_max<0x128>(v);
    return v;
}
// sum over a 16-lane row (stride-4 groups end up fully summed)
__device__ __forceinline__ float rowadd16(float v) {
    v = dpp_add<0x124>(v);
    v = dpp_add<0x128>(v);
    return v;
}

// Per-wave int64-vs-int32 detection: odd 32-bit words of first 64 entries all
// zero -> int64. Deterministic, identical in every wave.
__device__ __forceinline__ int detect64(const int* __restrict__ ei) {
    int l = (int)(threadIdx.x & 63);
    int v = ei[2 * l + 1];
    return (__ballot(v != 0) == 0ULL) ? 1 : 0;
}

// ---------------------------------------------------------------------------
// Histogram of destination nodes (including self-loops e in [E, E+N)).
__global__ void hist_kernel(const int* __restrict__ ei,
                            int* __restrict__ deg, int E, int E2) {
    int is64 = detect64(ei);
    for (int e = blockIdx.x * blockDim.x + threadIdx.x; e < E2;
         e += gridDim.x * blockDim.x) {
        int d;
        if (e < E) d = is64 ? ei[2 * (E + e)] : ei[E + e];
        else       d = e - E;
        atomicAdd(&deg[d], 1);
    }
}

// ---------------------------------------------------------------------------
// Hierarchical scan -> rowptr (+ cursor zeroing folded in).
__global__ void scan_local_kernel(const int* __restrict__ deg, int* __restrict__ incl,
                                  int* __restrict__ bsum, int N) {
    __shared__ int sm[256];
    int i = blockIdx.x * 256 + threadIdx.x;
    int v = (i < N) ? deg[i] : 0;
    sm[threadIdx.x] = v;
    __syncthreads();
    #pragma unroll
    for (int off = 1; off < 256; off <<= 1) {
        int t = ((int)threadIdx.x >= off) ? sm[threadIdx.x - off] : 0;
        __syncthreads();
        sm[threadIdx.x] += t;
        __syncthreads();
    }
    if (i < N) incl[i] = sm[threadIdx.x];
    if (threadIdx.x == 255) bsum[blockIdx.x] = sm[255];
}

__global__ void scan_bsum_kernel(int* __restrict__ bsum, int nb) {
    __shared__ int sm[256];
    __shared__ int running;
    if (threadIdx.x == 0) running = 0;
    __syncthreads();
    for (int base = 0; base < nb; base += 256) {
        int i = base + (int)threadIdx.x;
        int v = (i < nb) ? bsum[i] : 0;
        sm[threadIdx.x] = v;
        __syncthreads();
        #pragma unroll
        for (int off = 1; off < 256; off <<= 1) {
            int t = ((int)threadIdx.x >= off) ? sm[threadIdx.x - off] : 0;
            __syncthreads();
            sm[threadIdx.x] += t;
            __syncthreads();
        }
        if (i < nb) bsum[i] = running + sm[threadIdx.x] - v;   // exclusive
        __syncthreads();
        if (threadIdx.x == 0) running += sm[255];
        __syncthreads();
    }
}

__global__ void scan_final_kernel(const int* __restrict__ incl, const int* __restrict__ bsum,
                                  int* __restrict__ rowptr, int* __restrict__ cursor, int N) {
    int i = blockIdx.x * 256 + threadIdx.x;
    if (i < N) { rowptr[i + 1] = incl[i] + bsum[blockIdx.x]; cursor[i] = 0; }
    if (i == 0) rowptr[0] = 0;
}

// ---------------------------------------------------------------------------
// Scatter edges into CSR order (sorted by dst). cursor zeroed by scan_final.
__global__ void scatter_kernel(const int* __restrict__ ei,
                               const int* __restrict__ rowptr, int* __restrict__ cursor,
                               int* __restrict__ srcs, int E, int E2) {
    int is64 = detect64(ei);
    for (int e = blockIdx.x * blockDim.x + threadIdx.x; e < E2;
         e += gridDim.x * blockDim.x) {
        int s, d;
        if (e < E) {
            if (is64) { s = ei[2 * e]; d = ei[2 * (E + e)]; }
            else      { s = ei[e];     d = ei[E + e]; }
        } else {
            s = d = e - E;
        }
        int pos = rowptr[d] + atomicAdd(&cursor[d], 1);
        srcs[pos] = s;
    }
}

// ---------------------------------------------------------------------------
// Dual GEMM, register-tiled; OUTPUT IS HEAD-MAJOR: xl[h][n][48], xr[h][n][48].
template<int DIN>
__global__ __launch_bounds__(192) void gemm2t_kernel(
    const float* __restrict__ xin,
    const float* __restrict__ Wl, const float* __restrict__ bl,
    const float* __restrict__ Wr, const float* __restrict__ br,
    float* __restrict__ xl, float* __restrict__ xr, int N) {
    int t  = (int)threadIdx.x;
    int cg = t % 48;           // column group -> cols c0..c0+3
    int ng = t / 48;           // node group 0..3
    int c0 = cg * 4;
    int n0 = blockIdx.x * 16 + ng * 4;
    if (n0 >= N) return;
    int hh = c0 / 48;          // head of this column group (48%4==0 -> single head)
    int ch = c0 - hh * 48;     // channel within head

    f4 bLv = *(const f4*)&bl[c0];
    f4 bRv = *(const f4*)&br[c0];
    f4 accL[4], accR[4];
    #pragma unroll
    for (int i = 0; i < 4; ++i) { accL[i] = bLv; accR[i] = bRv; }

    if (n0 + 3 < N) {
        if (DIN == 3) {
            float xv[4][3];
            #pragma unroll
            for (int i = 0; i < 4; ++i) {
                const float* xp = xin + (size_t)(n0 + i) * 3;
                xv[i][0] = xp[0]; xv[i][1] = xp[1]; xv[i][2] = xp[2];
            }
            #pragma unroll
            for (int k = 0; k < 3; ++k) {
                f4 wl4 = *(const f4*)&Wl[k * FDIM + c0];
                f4 wr4 = *(const f4*)&Wr[k * FDIM + c0];
                #pragma unroll
                for (int i = 0; i < 4; ++i) {
                    float xs = xv[i][k];
                    accL[i] += xs * wl4;
                    accR[i] += xs * wr4;
                }
            }
        } else {
            #pragma unroll
            for (int kk = 0; kk < DIN; kk += 8) {
                float xv[4][8];
                #pragma unroll
                for (int i = 0; i < 4; ++i) {
                    const float* xp = xin + (size_t)(n0 + i) * DIN + kk;
                    f4 xa = *(const f4*)xp;
                    f4 xb = *(const f4*)(xp + 4);
                    #pragma unroll
                    for (int q = 0; q < 4; ++q) { xv[i][q] = xa[q]; xv[i][4 + q] = xb[q]; }
                }
                #pragma unroll
                for (int k = 0; k < 8; ++k) {
                    f4 wl4 = *(const f4*)&Wl[(kk + k) * FDIM + c0];
                    f4 wr4 = *(const f4*)&Wr[(kk + k) * FDIM + c0];
                    #pragma unroll
                    for (int i = 0; i < 4; ++i) {
                        float xs = xv[i][k];
                        accL[i] += xs * wl4;
                        accR[i] += xs * wr4;
                    }
                }
            }
        }
        #pragma unroll
        for (int i = 0; i < 4; ++i) {
            size_t o = ((size_t)hh * N + (n0 + i)) * HID + ch;
            *(f4*)&xl[o] = accL[i];
            *(f4*)&xr[o] = accR[i];
        }
    } else {
        for (int i = 0; i < 4; ++i) {
            int n = n0 + i;
            if (n >= N) break;
            f4 aL = bLv;
            f4 aR = bRv;
            for (int k = 0; k < DIN; ++k) {
                float xs = xin[(size_t)n * DIN + k];
                f4 wl4 = *(const f4*)&Wl[k * FDIM + c0];
                f4 wr4 = *(const f4*)&Wr[k * FDIM + c0];
                aL += xs * wl4;
                aR += xs * wr4;
            }
            size_t o = ((size_t)hh * N + n) * HID + ch;
            *(f4*)&xl[o] = aL;
            *(f4*)&xr[o] = aR;
        }
    }
}

// ---------------------------------------------------------------------------
// Head-partitioned GATv2 edge kernel with XCD affinity.
//   blockIdx -> xcd = bid%8 (HW round-robin), head = xcd>>1: each head's
//   9.6 MB gather table is touched by only 2 XCDs -> fetch floor 8x9.6=77MB.
//   Wave = 2 (node) halves; half-lane l5 = es*4+cq: es in [0,8) edge slots,
//   cq in [0,4) channel quarters (12 contiguous ch). Online softmax per
//   (node, head) with defer-max. Result 0.25*o atomic-added into psum[N][48].
#define SCORE_MASKED (-1e38f)
#define M_INIT       (-3e38f)
#define DEFER_THR    8.0f

__global__ __launch_bounds__(256) void gat_head_kernel(
    const float* __restrict__ xlh,   // [4][N][48]
    const float* __restrict__ xrh,   // [4][N][48]
    const float* __restrict__ att,   // [4][48]
    const int* __restrict__ rowptr, const int* __restrict__ srcs,
    float* __restrict__ psum,        // [N][48], pre-zeroed
    int N) {
    int bid = (int)blockIdx.x;
    int xcd = bid & 7;
    int h   = xcd >> 1;                        // head for this block (SGPR)
    int j   = (bid >> 3) * 2 + (xcd & 1);      // node-octet index for this head
    int wv  = (int)(threadIdx.x >> 6);
    int lane = (int)(threadIdx.x & 63);
    int half = lane >> 5;
    int l5 = lane & 31;
    int es = l5 >> 2;
    int cq = l5 & 3;
    int c0 = cq * 12;
    int n = j * 8 + wv * 2 + half;
    bool nvalid = (n < N);
    int nc = nvalid ? n : 0;

    const float* hb = xlh + (size_t)h * N * HID;       // head table base (SGPR)
    const float* xrp = xrh + (size_t)h * N * HID + (size_t)nc * HID + c0;
    f4 r0 = *(const f4*)xrp;
    f4 r1 = *(const f4*)(xrp + 4);
    f4 r2 = *(const f4*)(xrp + 8);
    f4 a0 = *(const f4*)&att[h * HID + c0];
    f4 a1 = *(const f4*)&att[h * HID + c0 + 4];
    f4 a2 = *(const f4*)&att[h * HID + c0 + 8];

    int e0 = nvalid ? rowptr[n] : 0;
    int e1 = nvalid ? rowptr[n + 1] : 0;
    int elast = e1 - 1;

    float m = M_INIT, dn = 0.f;
    f4 acc0 = {0.f, 0.f, 0.f, 0.f}, acc1 = acc0, acc2 = acc0;

    for (int e = e0; e < e1; e += 8) {
        int idx = e + es;
        int k = (idx < e1) ? idx : elast;
        int s = srcs[k];
        const float* p = hb + (size_t)s * HID + c0;
        f4 A0 = *(const f4*)p;
        f4 A1 = *(const f4*)(p + 4);
        f4 A2 = *(const f4*)(p + 8);

        float sc = 0.f;
        #pragma unroll
        for (int q = 0; q < 4; ++q) {
            float t;
            t = A0[q] + r0[q]; sc = fmaf(fmaxf(t, NEG_SLOPE * t), a0[q], sc);
            t = A1[q] + r1[q]; sc = fmaf(fmaxf(t, NEG_SLOPE * t), a1[q], sc);
            t = A2[q] + r2[q]; sc = fmaf(fmaxf(t, NEG_SLOPE * t), a2[q], sc);
        }
        sc = red_cq(sc);                       // full 48-ch dot for (n,h,es)
        sc = (idx < e1) ? sc : SCORE_MASKED;

        float bmax = rowmax16(sc);             // max over es0-3 / es4-7 row
        bmax = fmaxf(bmax, __shfl_xor(bmax, 16));  // combine the node's 2 rows
        if (__any(bmax > m + DEFER_THR)) {     // rare after first batch
            float nm = fmaxf(m, bmax);
            float s_ = __expf(m - nm);         // m=M_INIT -> 0
            dn *= s_; acc0 *= s_; acc1 *= s_; acc2 *= s_;
            m = nm;
        }
        float q_ = __expf(sc - m);             // masked -> 0
        dn += q_;
        acc0 += q_ * A0;
        acc1 += q_ * A1;
        acc2 += q_ * A2;
    }

    // reduce over the 8 edge slots (rowadd within 16-row, then cross-row)
    dn = rowadd16(dn); dn += __shfl_xor(dn, 16);
    #pragma unroll
    for (int q = 0; q < 4; ++q) {
        float v;
        v = rowadd16(acc0[q]); v += __shfl_xor(v, 16); acc0[q] = v;
        v = rowadd16(acc1[q]); v += __shfl_xor(v, 16); acc1[q] = v;
        v = rowadd16(acc2[q]); v += __shfl_xor(v, 16); acc2[q] = v;
    }

    if (nvalid && es == 0) {
        float w = 0.25f / (dn + 1e-16f);       // head-mean factor folded in
        float* po = psum + (size_t)n * HID + c0;
        #pragma unroll
        for (int q = 0; q < 4; ++q) {
            atomicAdd(&po[q],     acc0[q] * w);
            atomicAdd(&po[4 + q], acc1[q] * w);
            atomicAdd(&po[8 + q], acc2[q] * w);
        }
    }
}

// ---------------------------------------------------------------------------
// Combine (non-final): x = elu(psum + bias), in place (psum doubles as next
// layer's GEMM input). Thread = (node, channel-quarter).
__global__ void combine_kernel(float* __restrict__ psum,
                               const float* __restrict__ bias, int N) {
    int t = blockIdx.x * 256 + threadIdx.x;
    int n = t >> 2, cq = t & 3;
    if (n >= N) return;
    int c0 = cq * 12;
    float* p = psum + (size_t)n * HID + c0;
    f4 v0 = *(const f4*)p + *(const f4*)&bias[c0];
    f4 v1 = *(const f4*)(p + 4) + *(const f4*)&bias[c0 + 4];
    f4 v2 = *(const f4*)(p + 8) + *(const f4*)&bias[c0 + 8];
    #pragma unroll
    for (int q = 0; q < 4; ++q) {
        v0[q] = (v0[q] > 0.f) ? v0[q] : (__expf(v0[q]) - 1.f);
        v1[q] = (v1[q] > 0.f) ? v1[q] : (__expf(v1[q]) - 1.f);
        v2[q] = (v2[q] > 0.f) ? v2[q] : (__expf(v2[q]) - 1.f);
    }
    *(f4*)p = v0;
    *(f4*)(p + 4) = v1;
    *(f4*)(p + 8) = v2;
}

// Combine (final): elu(psum+bias) -> dot head_w -> +head_b -> relu -> out[n].
__global__ void combine_final_kernel(const float* __restrict__ psum,
                                     const float* __restrict__ bias,
                                     const float* __restrict__ head_w,
                                     const float* __restrict__ head_b,
                                     float* __restrict__ out, int N) {
    int t = blockIdx.x * 256 + threadIdx.x;
    int n = t >> 2, cq = t & 3;
    if (n >= N) return;
    int c0 = cq * 12;
    const float* p = psum + (size_t)n * HID + c0;
    f4 v0 = *(const f4*)p + *(const f4*)&bias[c0];
    f4 v1 = *(const f4*)(p + 4) + *(const f4*)&bias[c0 + 4];
    f4 v2 = *(const f4*)(p + 8) + *(const f4*)&bias[c0 + 8];
    f4 w0 = *(const f4*)&head_w[c0];
    f4 w1 = *(const f4*)&head_w[c0 + 4];
    f4 w2 = *(const f4*)&head_w[c0 + 8];
    float d = 0.f;
    #pragma unroll
    for (int q = 0; q < 4; ++q) {
        float e0 = (v0[q] > 0.f) ? v0[q] : (__expf(v0[q]) - 1.f);
        float e1 = (v1[q] > 0.f) ? v1[q] : (__expf(v1[q]) - 1.f);
        float e2 = (v2[q] > 0.f) ? v2[q] : (__expf(v2[q]) - 1.f);
        d += e0 * w0[q] + e1 * w1[q] + e2 * w2[q];
    }
    d = red_cq(d);                        // quad shares node n
    if (cq == 0) {
        float v = d + head_b[0];
        out[n] = (v > 0.f) ? v : 0.f;
    }
}

// ---------------------------------------------------------------------------
extern "C" void kernel_launch(void* const* d_in, const int* in_sizes, int n_in,
                              void* d_out, int out_size, void* d_ws, size_t ws_size,
                              hipStream_t stream) {
    const float* x0 = (const float*)d_in[0];
    const int*   ei = (const int*)d_in[1];

    const int N  = in_sizes[0] / 3;        // 50000
    const int E  = in_sizes[1] / 2;        // 800000
    const int E2 = E + N;                  // edges incl. self-loops

    const float* Wl[3];  const float* bl[3];
    const float* Wr[3];  const float* br[3];
    const float* att[3]; const float* bias[3];
    for (int li = 0; li < 3; ++li) {
        int b = 2 + 6 * li;
        Wl[li]   = (const float*)d_in[b + 0];
        bl[li]   = (const float*)d_in[b + 1];
        Wr[li]   = (const float*)d_in[b + 2];
        br[li]   = (const float*)d_in[b + 3];
        att[li]  = (const float*)d_in[b + 4];
        bias[li] = (const float*)d_in[b + 5];
    }
    const float* head_w = (const float*)d_in[20];
    const float* head_b = (const float*)d_in[21];
    float* out = (float*)d_out;

    // ---- workspace carve-up (256B aligned) ----
    size_t off = 0;
    auto alloc = [&](size_t bytes) -> void* {
        void* p = (char*)d_ws + off;
        off = (off + bytes + 255) & ~(size_t)255;
        return p;
    };
    const int nb = (N + 255) / 256;
    int*   deg    = (int*)alloc((size_t)N * sizeof(int));        // reused as cursor
    int*   incl   = (int*)alloc((size_t)N * sizeof(int));
    int*   bsum   = (int*)alloc((size_t)nb * sizeof(int));
    int*   rowptr = (int*)alloc((size_t)(N + 1) * sizeof(int));
    int*   srcs   = (int*)alloc((size_t)E2 * sizeof(int));
    float* xlb    = (float*)alloc((size_t)N * FDIM * sizeof(float));  // head-major [4][N][48]
    float* xrb    = (float*)alloc((size_t)N * FDIM * sizeof(float));  // head-major [4][N][48]
    float* psum   = (float*)alloc((size_t)N * HID * sizeof(float));   // head-mean accumulator / layer input
    (void)ws_size;

    // ---- build CSR (layer-invariant) ----
    (void)hipMemsetAsync(deg, 0, (size_t)N * sizeof(int), stream);
    hist_kernel<<<2048, 256, 0, stream>>>(ei, deg, E, E2);
    scan_local_kernel<<<nb, 256, 0, stream>>>(deg, incl, bsum, N);
    scan_bsum_kernel<<<1, 256, 0, stream>>>(bsum, nb);
    scan_final_kernel<<<nb, 256, 0, stream>>>(incl, bsum, rowptr, deg, N);
    scatter_kernel<<<2048, 256, 0, stream>>>(ei, rowptr, deg, srcs, E, E2);

    int gemm_blocks = (N + 15) / 16;
    int gat_blocks  = ((((N + 7) / 8) + 1) / 2) * 8;   // head-partitioned grid
    int cmb_blocks  = (N * 4 + 255) / 256;
    size_t psum_bytes = (size_t)N * HID * sizeof(float);

    // ---- layer 0 (din=3) ----
    (void)hipMemsetAsync(psum, 0, psum_bytes, stream);
    gemm2t_kernel<3><<<gemm_blocks, 192, 0, stream>>>(x0, Wl[0], bl[0], Wr[0], br[0], xlb, xrb, N);
    gat_head_kernel<<<gat_blocks, 256, 0, stream>>>(xlb, xrb, att[0], rowptr, srcs, psum, N);
    combine_kernel<<<cmb_blocks, 256, 0, stream>>>(psum, bias[0], N);

    // ---- layer 1 (din=48) ----
    gemm2t_kernel<HID><<<gemm_blocks, 192, 0, stream>>>(psum, Wl[1], bl[1], Wr[1], br[1], xlb, xrb, N);
    (void)hipMemsetAsync(psum, 0, psum_bytes, stream);
    gat_head_kernel<<<gat_blocks, 256, 0, stream>>>(xlb, xrb, att[1], rowptr, srcs, psum, N);
    combine_kernel<<<cmb_blocks, 256, 0, stream>>>(psum, bias[1], N);

    // ---- layer 2 (din=48) + fused head MLP + ReLU ----
    gemm2t_kernel<HID><<<gemm_blocks, 192, 0, stream>>>(psum, Wl[2], bl[2], Wr[2], br[2], xlb, xrb, N);
    (void)hipMemsetAsync(psum, 0, psum_bytes, stream);
    gat_head_kernel<<<gat_blocks, 256, 0, stream>>>(xlb, xrb, att[2], rowptr, srcs, psum, N);
    combine_final_kernel<<<cmb_blocks, 256, 0, stream>>>(psum, bias[2], head_w, head_b, out, N);

    (void)n_in; (void)out_size;
}

// Round 9
// 642.683 us; speedup vs baseline: 2.4449x; 2.4449x over previous
//
#include <hip/hip_runtime.h>
#include <hip/hip_bf16.h>
#include <math.h>

#define HEADS 4
#define HID 48
#define FDIM 192   // HEADS*HID
#define NEG_SLOPE 0.2f

typedef float f4 __attribute__((ext_vector_type(4)));

// ---------------------------------------------------------------------------
// DPP helpers (VALU-pipe cross-lane).
template<int CTRL>
__device__ __forceinline__ float dpp_add(float v) {
    int t = __builtin_amdgcn_update_dpp(0, __float_as_int(v), CTRL, 0xF, 0xF, true);
    return v + __int_as_float(t);
}
template<int CTRL>
__device__ __forceinline__ float dpp_max(float v) {
    int t = __builtin_amdgcn_update_dpp(0, __float_as_int(v), CTRL, 0xF, 0xF, true);
    return fmaxf(v, __int_as_float(t));
}
// sum over the 4 lanes of a quad (cq axis)
__device__ __forceinline__ float red_cq(float v) {
    v = dpp_add<0xB1>(v);
    v = dpp_add<0x4E>(v);
    return v;
}
// max over a 16-lane row
__device__ __forceinline__ float rowmax16(float v) {
    v = dpp_max<0x124>(v);
    v = dpp_max<0x128>(v);
    return v;
}
// sum over stride-4 lane groups within a 16-lane row (preserves cq = lane&3)
__device__ __forceinline__ float rowadd16(float v) {
    v = dpp_add<0x124>(v);
    v = dpp_add<0x128>(v);
    return v;
}

// Per-wave int64-vs-int32 detection.
__device__ __forceinline__ int detect64(const int* __restrict__ ei) {
    int l = (int)(threadIdx.x & 63);
    int v = ei[2 * l + 1];
    return (__ballot(v != 0) == 0ULL) ? 1 : 0;
}

// ---------------------------------------------------------------------------
__global__ void hist_kernel(const int* __restrict__ ei,
                            int* __restrict__ deg, int E, int E2) {
    int is64 = detect64(ei);
    for (int e = blockIdx.x * blockDim.x + threadIdx.x; e < E2;
         e += gridDim.x * blockDim.x) {
        int d;
        if (e < E) d = is64 ? ei[2 * (E + e)] : ei[E + e];
        else       d = e - E;
        atomicAdd(&deg[d], 1);
    }
}

__global__ void scan_local_kernel(const int* __restrict__ deg, int* __restrict__ incl,
                                  int* __restrict__ bsum, int N) {
    __shared__ int sm[256];
    int i = blockIdx.x * 256 + threadIdx.x;
    int v = (i < N) ? deg[i] : 0;
    sm[threadIdx.x] = v;
    __syncthreads();
    #pragma unroll
    for (int off = 1; off < 256; off <<= 1) {
        int t = ((int)threadIdx.x >= off) ? sm[threadIdx.x - off] : 0;
        __syncthreads();
        sm[threadIdx.x] += t;
        __syncthreads();
    }
    if (i < N) incl[i] = sm[threadIdx.x];
    if (threadIdx.x == 255) bsum[blockIdx.x] = sm[255];
}

__global__ void scan_bsum_kernel(int* __restrict__ bsum, int nb) {
    __shared__ int sm[256];
    __shared__ int running;
    if (threadIdx.x == 0) running = 0;
    __syncthreads();
    for (int base = 0; base < nb; base += 256) {
        int i = base + (int)threadIdx.x;
        int v = (i < nb) ? bsum[i] : 0;
        sm[threadIdx.x] = v;
        __syncthreads();
        #pragma unroll
        for (int off = 1; off < 256; off <<= 1) {
            int t = ((int)threadIdx.x >= off) ? sm[threadIdx.x - off] : 0;
            __syncthreads();
            sm[threadIdx.x] += t;
            __syncthreads();
        }
        if (i < nb) bsum[i] = running + sm[threadIdx.x] - v;   // exclusive
        __syncthreads();
        if (threadIdx.x == 0) running += sm[255];
        __syncthreads();
    }
}

__global__ void scan_final_kernel(const int* __restrict__ incl, const int* __restrict__ bsum,
                                  int* __restrict__ rowptr, int* __restrict__ cursor, int N) {
    int i = blockIdx.x * 256 + threadIdx.x;
    if (i < N) { rowptr[i + 1] = incl[i] + bsum[blockIdx.x]; cursor[i] = 0; }
    if (i == 0) rowptr[0] = 0;
}

__global__ void scatter_kernel(const int* __restrict__ ei,
                               const int* __restrict__ rowptr, int* __restrict__ cursor,
                               int* __restrict__ srcs, int E, int E2) {
    int is64 = detect64(ei);
    for (int e = blockIdx.x * blockDim.x + threadIdx.x; e < E2;
         e += gridDim.x * blockDim.x) {
        int s, d;
        if (e < E) {
            if (is64) { s = ei[2 * e]; d = ei[2 * (E + e)]; }
            else      { s = ei[e];     d = ei[E + e]; }
        } else {
            s = d = e - E;
        }
        int pos = rowptr[d] + atomicAdd(&cursor[d], 1);
        srcs[pos] = s;
    }
}

// ---------------------------------------------------------------------------
// Dual GEMM, register-tiled; OUTPUT IS HEAD-MAJOR: xl[h][n][48], xr[h][n][48].
template<int DIN>
__global__ __launch_bounds__(192) void gemm2t_kernel(
    const float* __restrict__ xin,
    const float* __restrict__ Wl, const float* __restrict__ bl,
    const float* __restrict__ Wr, const float* __restrict__ br,
    float* __restrict__ xl, float* __restrict__ xr, int N) {
    int t  = (int)threadIdx.x;
    int cg = t % 48;           // column group -> cols c0..c0+3
    int ng = t / 48;           // node group 0..3
    int c0 = cg * 4;
    int n0 = blockIdx.x * 16 + ng * 4;
    if (n0 >= N) return;
    int hh = c0 / 48;          // head of this column group
    int ch = c0 - hh * 48;     // channel within head

    f4 bLv = *(const f4*)&bl[c0];
    f4 bRv = *(const f4*)&br[c0];
    f4 accL[4], accR[4];
    #pragma unroll
    for (int i = 0; i < 4; ++i) { accL[i] = bLv; accR[i] = bRv; }

    if (n0 + 3 < N) {
        if (DIN == 3) {
            float xv[4][3];
            #pragma unroll
            for (int i = 0; i < 4; ++i) {
                const float* xp = xin + (size_t)(n0 + i) * 3;
                xv[i][0] = xp[0]; xv[i][1] = xp[1]; xv[i][2] = xp[2];
            }
            #pragma unroll
            for (int k = 0; k < 3; ++k) {
                f4 wl4 = *(const f4*)&Wl[k * FDIM + c0];
                f4 wr4 = *(const f4*)&Wr[k * FDIM + c0];
                #pragma unroll
                for (int i = 0; i < 4; ++i) {
                    float xs = xv[i][k];
                    accL[i] += xs * wl4;
                    accR[i] += xs * wr4;
                }
            }
        } else {
            #pragma unroll
            for (int kk = 0; kk < DIN; kk += 8) {
                float xv[4][8];
                #pragma unroll
                for (int i = 0; i < 4; ++i) {
                    const float* xp = xin + (size_t)(n0 + i) * DIN + kk;
                    f4 xa = *(const f4*)xp;
                    f4 xb = *(const f4*)(xp + 4);
                    #pragma unroll
                    for (int q = 0; q < 4; ++q) { xv[i][q] = xa[q]; xv[i][4 + q] = xb[q]; }
                }
                #pragma unroll
                for (int k = 0; k < 8; ++k) {
                    f4 wl4 = *(const f4*)&Wl[(kk + k) * FDIM + c0];
                    f4 wr4 = *(const f4*)&Wr[(kk + k) * FDIM + c0];
                    #pragma unroll
                    for (int i = 0; i < 4; ++i) {
                        float xs = xv[i][k];
                        accL[i] += xs * wl4;
                        accR[i] += xs * wr4;
                    }
                }
            }
        }
        #pragma unroll
        for (int i = 0; i < 4; ++i) {
            size_t o = ((size_t)hh * N + (n0 + i)) * HID + ch;
            *(f4*)&xl[o] = accL[i];
            *(f4*)&xr[o] = accR[i];
        }
    } else {
        for (int i = 0; i < 4; ++i) {
            int n = n0 + i;
            if (n >= N) break;
            f4 aL = bLv;
            f4 aR = bRv;
            for (int k = 0; k < DIN; ++k) {
                float xs = xin[(size_t)n * DIN + k];
                f4 wl4 = *(const f4*)&Wl[k * FDIM + c0];
                f4 wr4 = *(const f4*)&Wr[k * FDIM + c0];
                aL += xs * wl4;
                aR += xs * wr4;
            }
            size_t o = ((size_t)hh * N + n) * HID + ch;
            *(f4*)&xl[o] = aL;
            *(f4*)&xr[o] = aR;
        }
    }
}

// ---------------------------------------------------------------------------
// Head-partitioned GATv2 edge kernel with XCD affinity, NO atomics.
//   bid = g*8 + x ; x -> XCD (HW round-robin), head = x>>1: each head's
//   9.6 MB gather table is touched by only 2 XCDs.
//   Wave = one (node, head): lane = es*4+cq, es in [0,16) edge slots,
//   cq in [0,4) channel quarters (12 contiguous ch). 16 edges/iter.
//   Result o/denom written with PLAIN stores into oh[h][n][48]
//   (oh aliases xr: slot (h,n) is read at prologue / written at epilogue
//   by exactly the one wave that owns it).
#define SCORE_MASKED (-1e38f)
#define M_INIT       (-3e38f)
#define DEFER_THR    8.0f

__global__ __launch_bounds__(256) void gat_head_kernel(
    const float* __restrict__ xlh,   // [4][N][48]
    const float* __restrict__ xrh,   // [4][N][48]  (aliased as oh output)
    const float* __restrict__ att,   // [4][48]
    const int* __restrict__ rowptr, const int* __restrict__ srcs,
    float* __restrict__ oh,          // [4][N][48]  == xrh
    int N) {
    int bid = (int)blockIdx.x;
    int x   = bid & 7;                 // XCD (assumed round-robin)
    int h   = x >> 1;                  // head for this block (SGPR)
    int j   = (bid >> 3) * 2 + (x & 1);
    int wv  = (int)(threadIdx.x >> 6);
    int n   = j * 4 + wv;
    if (n >= N) return;
    int lane = (int)(threadIdx.x & 63);
    int es = lane >> 2;                // edge slot [0,16)
    int cq = lane & 3;                 // channel quarter
    int c0 = cq * 12;

    const float* hb = xlh + (size_t)h * N * HID;          // head table base
    const float* xrp = xrh + ((size_t)h * N + n) * HID + c0;
    f4 r0 = *(const f4*)xrp;
    f4 r1 = *(const f4*)(xrp + 4);
    f4 r2 = *(const f4*)(xrp + 8);
    f4 a0 = *(const f4*)&att[h * HID + c0];
    f4 a1 = *(const f4*)&att[h * HID + c0 + 4];
    f4 a2 = *(const f4*)&att[h * HID + c0 + 8];

    int e0 = rowptr[n], e1 = rowptr[n + 1];
    int elast = e1 - 1;

    float m = M_INIT, dn = 0.f;
    f4 acc0 = {0.f, 0.f, 0.f, 0.f}, acc1 = acc0, acc2 = acc0;

    for (int e = e0; e < e1; e += 16) {
        int idx = e + es;
        int k = (idx < e1) ? idx : elast;
        int s = srcs[k];
        const float* p = hb + (size_t)s * HID + c0;
        f4 A0 = *(const f4*)p;
        f4 A1 = *(const f4*)(p + 4);
        f4 A2 = *(const f4*)(p + 8);

        float sc = 0.f;
        #pragma unroll
        for (int q = 0; q < 4; ++q) {
            float t;
            t = A0[q] + r0[q]; sc = fmaf(fmaxf(t, NEG_SLOPE * t), a0[q], sc);
            t = A1[q] + r1[q]; sc = fmaf(fmaxf(t, NEG_SLOPE * t), a1[q], sc);
            t = A2[q] + r2[q]; sc = fmaf(fmaxf(t, NEG_SLOPE * t), a2[q], sc);
        }
        sc = red_cq(sc);                       // full 48-ch dot for (n,h,es)
        sc = (idx < e1) ? sc : SCORE_MASKED;

        if (__any(sc > m + DEFER_THR)) {       // rare after first batch
            float bm = rowmax16(sc);
            bm = fmaxf(bm, __shfl_xor(bm, 16));
            bm = fmaxf(bm, __shfl_xor(bm, 32));
            float nm = fmaxf(m, bm);
            float s_ = __expf(m - nm);         // m=M_INIT -> 0
            dn *= s_; acc0 *= s_; acc1 *= s_; acc2 *= s_;
            m = nm;
        }
        float q_ = __expf(sc - m);             // masked -> 0
        dn += q_;
        acc0 += q_ * A0;
        acc1 += q_ * A1;
        acc2 += q_ * A2;
    }

    // Reduce over the 16 edge slots. rowadd16 sums stride-4 groups within a
    // 16-lane row (preserves cq); xor16/xor32 sum the 4 rows. Each edge is
    // counted exactly ONCE per cq lane -> dn is already the true denominator.
    dn = rowadd16(dn); dn += __shfl_xor(dn, 16); dn += __shfl_xor(dn, 32);
    #pragma unroll
    for (int q = 0; q < 4; ++q) {
        float v;
        v = rowadd16(acc0[q]); v += __shfl_xor(v, 16); v += __shfl_xor(v, 32); acc0[q] = v;
        v = rowadd16(acc1[q]); v += __shfl_xor(v, 16); v += __shfl_xor(v, 32); acc1[q] = v;
        v = rowadd16(acc2[q]); v += __shfl_xor(v, 16); v += __shfl_xor(v, 32); acc2[q] = v;
    }

    if (es == 0) {                              // 4 lanes store 12 floats each
        float w = 1.0f / (dn + 1e-16f);
        float* po = oh + ((size_t)h * N + n) * HID + c0;
        *(f4*)po       = acc0 * w;
        *(f4*)(po + 4) = acc1 * w;
        *(f4*)(po + 8) = acc2 * w;
    }
}

// ---------------------------------------------------------------------------
// Combine (non-final): psum = elu(0.25*sum_h oh[h] + bias). Thread=(n,cq).
__global__ void combine_kernel(const float* __restrict__ oh,
                               const float* __restrict__ bias,
                               float* __restrict__ psum, int N) {
    int t = blockIdx.x * 256 + threadIdx.x;
    int n = t >> 2, cq = t & 3;
    if (n >= N) return;
    int c0 = cq * 12;
    f4 v0 = {0.f,0.f,0.f,0.f}, v1 = v0, v2 = v0;
    #pragma unroll
    for (int h = 0; h < HEADS; ++h) {
        const float* p = oh + ((size_t)h * N + n) * HID + c0;
        v0 += *(const f4*)p;
        v1 += *(const f4*)(p + 4);
        v2 += *(const f4*)(p + 8);
    }
    v0 = 0.25f * v0 + *(const f4*)&bias[c0];
    v1 = 0.25f * v1 + *(const f4*)&bias[c0 + 4];
    v2 = 0.25f * v2 + *(const f4*)&bias[c0 + 8];
    #pragma unroll
    for (int q = 0; q < 4; ++q) {
        v0[q] = (v0[q] > 0.f) ? v0[q] : (__expf(v0[q]) - 1.f);
        v1[q] = (v1[q] > 0.f) ? v1[q] : (__expf(v1[q]) - 1.f);
        v2[q] = (v2[q] > 0.f) ? v2[q] : (__expf(v2[q]) - 1.f);
    }
    float* pd = psum + (size_t)n * HID + c0;
    *(f4*)pd       = v0;
    *(f4*)(pd + 4) = v1;
    *(f4*)(pd + 8) = v2;
}

// Combine (final): elu(mean+bias) -> dot head_w -> +head_b -> relu -> out[n].
__global__ void combine_final_kernel(const float* __restrict__ oh,
                                     const float* __restrict__ bias,
                                     const float* __restrict__ head_w,
                                     const float* __restrict__ head_b,
                                     float* __restrict__ out, int N) {
    int t = blockIdx.x * 256 + threadIdx.x;
    int n = t >> 2, cq = t & 3;
    if (n >= N) return;
    int c0 = cq * 12;
    f4 v0 = {0.f,0.f,0.f,0.f}, v1 = v0, v2 = v0;
    #pragma unroll
    for (int h = 0; h < HEADS; ++h) {
        const float* p = oh + ((size_t)h * N + n) * HID + c0;
        v0 += *(const f4*)p;
        v1 += *(const f4*)(p + 4);
        v2 += *(const f4*)(p + 8);
    }
    v0 = 0.25f * v0 + *(const f4*)&bias[c0];
    v1 = 0.25f * v1 + *(const f4*)&bias[c0 + 4];
    v2 = 0.25f * v2 + *(const f4*)&bias[c0 + 8];
    f4 w0 = *(const f4*)&head_w[c0];
    f4 w1 = *(const f4*)&head_w[c0 + 4];
    f4 w2 = *(const f4*)&head_w[c0 + 8];
    float d = 0.f;
    #pragma unroll
    for (int q = 0; q < 4; ++q) {
        float e0 = (v0[q] > 0.f) ? v0[q] : (__expf(v0[q]) - 1.f);
        float e1 = (v1[q] > 0.f) ? v1[q] : (__expf(v1[q]) - 1.f);
        float e2 = (v2[q] > 0.f) ? v2[q] : (__expf(v2[q]) - 1.f);
        d += e0 * w0[q] + e1 * w1[q] + e2 * w2[q];
    }
    d = red_cq(d);                        // quad shares node n
    if (cq == 0) {
        float v = d + head_b[0];
        out[n] = (v > 0.f) ? v : 0.f;
    }
}

// ---------------------------------------------------------------------------
extern "C" void kernel_launch(void* const* d_in, const int* in_sizes, int n_in,
                              void* d_out, int out_size, void* d_ws, size_t ws_size,
                              hipStream_t stream) {
    const float* x0 = (const float*)d_in[0];
    const int*   ei = (const int*)d_in[1];

    const int N  = in_sizes[0] / 3;        // 50000
    const int E  = in_sizes[1] / 2;        // 800000
    const int E2 = E + N;                  // edges incl. self-loops

    const float* Wl[3];  const float* bl[3];
    const float* Wr[3];  const float* br[3];
    const float* att[3]; const float* bias[3];
    for (int li = 0; li < 3; ++li) {
        int b = 2 + 6 * li;
        Wl[li]   = (const float*)d_in[b + 0];
        bl[li]   = (const float*)d_in[b + 1];
        Wr[li]   = (const float*)d_in[b + 2];
        br[li]   = (const float*)d_in[b + 3];
        att[li]  = (const float*)d_in[b + 4];
        bias[li] = (const float*)d_in[b + 5];
    }
    const float* head_w = (const float*)d_in[20];
    const float* head_b = (const float*)d_in[21];
    float* out = (float*)d_out;

    // ---- workspace carve-up (256B aligned) ----
    size_t off = 0;
    auto alloc = [&](size_t bytes) -> void* {
        void* p = (char*)d_ws + off;
        off = (off + bytes + 255) & ~(size_t)255;
        return p;
    };
    const int nb = (N + 255) / 256;
    int*   deg    = (int*)alloc((size_t)N * sizeof(int));        // reused as cursor
    int*   incl   = (int*)alloc((size_t)N * sizeof(int));
    int*   bsum   = (int*)alloc((size_t)nb * sizeof(int));
    int*   rowptr = (int*)alloc((size_t)(N + 1) * sizeof(int));
    int*   srcs   = (int*)alloc((size_t)E2 * sizeof(int));
    float* xlb    = (float*)alloc((size_t)N * FDIM * sizeof(float));  // [4][N][48]
    float* xrob   = (float*)alloc((size_t)N * FDIM * sizeof(float));  // xr / oh shared [4][N][48]
    float* psum   = (float*)alloc((size_t)N * HID * sizeof(float));   // layer activation [N][48]
    (void)ws_size;

    // ---- build CSR (layer-invariant) ----
    (void)hipMemsetAsync(deg, 0, (size_t)N * sizeof(int), stream);
    hist_kernel<<<2048, 256, 0, stream>>>(ei, deg, E, E2);
    scan_local_kernel<<<nb, 256, 0, stream>>>(deg, incl, bsum, N);
    scan_bsum_kernel<<<1, 256, 0, stream>>>(bsum, nb);
    scan_final_kernel<<<nb, 256, 0, stream>>>(incl, bsum, rowptr, deg, N);
    scatter_kernel<<<2048, 256, 0, stream>>>(ei, rowptr, deg, srcs, E, E2);

    int gemm_blocks = (N + 15) / 16;
    int G = (N + 7) / 8;
    int gat_blocks  = 8 * G;               // bid%8 -> XCD, head = (bid%8)>>1
    int cmb_blocks  = (N * 4 + 255) / 256;

    // ---- layer 0 (din=3) ----
    gemm2t_kernel<3><<<gemm_blocks, 192, 0, stream>>>(x0, Wl[0], bl[0], Wr[0], br[0], xlb, xrob, N);
    gat_head_kernel<<<gat_blocks, 256, 0, stream>>>(xlb, xrob, att[0], rowptr, srcs, xrob, N);
    combine_kernel<<<cmb_blocks, 256, 0, stream>>>(xrob, bias[0], psum, N);

    // ---- layer 1 (din=48) ----
    gemm2t_kernel<HID><<<gemm_blocks, 192, 0, stream>>>(psum, Wl[1], bl[1], Wr[1], br[1], xlb, xrob, N);
    gat_head_kernel<<<gat_blocks, 256, 0, stream>>>(xlb, xrob, att[1], rowptr, srcs, xrob, N);
    combine_kernel<<<cmb_blocks, 256, 0, stream>>>(xrob, bias[1], psum, N);

    // ---- layer 2 (din=48) + fused head MLP + ReLU ----
    gemm2t_kernel<HID><<<gemm_blocks, 192, 0, stream>>>(psum, Wl[2], bl[2], Wr[2], br[2], xlb, xrob, N);
    gat_head_kernel<<<gat_blocks, 256, 0, stream>>>(xlb, xrob, att[2], rowptr, srcs, xrob, N);
    combine_final_kernel<<<cmb_blocks, 256, 0, stream>>>(xrob, bias[2], head_w, head_b, out, N);

    (void)n_in; (void)out_size;
}

// Round 10
// 495.445 us; speedup vs baseline: 3.1714x; 1.2972x over previous
//
#include <hip/hip_runtime.h>
#include <hip/hip_bf16.h>
#include <math.h>

#define HEADS 4
#define HID 48
#define FDIM 192   // HEADS*HID
#define NEG_SLOPE 0.2f

typedef float f4 __attribute__((ext_vector_type(4)));

// ---------------------------------------------------------------------------
// DPP helpers: 16-lane sum reduction entirely on the VALU pipe.
template<int CTRL>
__device__ __forceinline__ float dpp_add(float v) {
    int t = __builtin_amdgcn_update_dpp(0, __float_as_int(v), CTRL, 0xF, 0xF, true);
    return v + __int_as_float(t);
}
__device__ __forceinline__ float red16(float v) {
    v = dpp_add<0xB1>(v);    // quad_perm xor1
    v = dpp_add<0x4E>(v);    // quad_perm xor2
    v = dpp_add<0x124>(v);   // row_ror:4
    v = dpp_add<0x128>(v);   // row_ror:8
    return v;   // all 16 lanes of the row-group hold the full sum
}

// Per-wave int64-vs-int32 detection: odd 32-bit words of first 64 entries all
// zero -> int64. Deterministic, identical in every wave.
__device__ __forceinline__ int detect64(const int* __restrict__ ei) {
    int l = (int)(threadIdx.x & 63);
    int v = ei[2 * l + 1];
    return (__ballot(v != 0) == 0ULL) ? 1 : 0;
}

// ---------------------------------------------------------------------------
// Histogram of destination nodes (including self-loops e in [E, E+N)).
__global__ void hist_kernel(const int* __restrict__ ei,
                            int* __restrict__ deg, int E, int E2) {
    int is64 = detect64(ei);
    for (int e = blockIdx.x * blockDim.x + threadIdx.x; e < E2;
         e += gridDim.x * blockDim.x) {
        int d;
        if (e < E) d = is64 ? ei[2 * (E + e)] : ei[E + e];
        else       d = e - E;
        atomicAdd(&deg[d], 1);
    }
}

// ---------------------------------------------------------------------------
// Hierarchical scan: (A) per-block inclusive scan + block sums,
// (B) single-block exclusive scan of block sums, (C) add offsets -> rowptr
//     (also zeroes the scatter cursor, saving a memset dispatch).
__global__ void scan_local_kernel(const int* __restrict__ deg, int* __restrict__ incl,
                                  int* __restrict__ bsum, int N) {
    __shared__ int sm[256];
    int i = blockIdx.x * 256 + threadIdx.x;
    int v = (i < N) ? deg[i] : 0;
    sm[threadIdx.x] = v;
    __syncthreads();
    #pragma unroll
    for (int off = 1; off < 256; off <<= 1) {
        int t = ((int)threadIdx.x >= off) ? sm[threadIdx.x - off] : 0;
        __syncthreads();
        sm[threadIdx.x] += t;
        __syncthreads();
    }
    if (i < N) incl[i] = sm[threadIdx.x];
    if (threadIdx.x == 255) bsum[blockIdx.x] = sm[255];
}

__global__ void scan_bsum_kernel(int* __restrict__ bsum, int nb) {
    __shared__ int sm[256];
    __shared__ int running;
    if (threadIdx.x == 0) running = 0;
    __syncthreads();
    for (int base = 0; base < nb; base += 256) {
        int i = base + (int)threadIdx.x;
        int v = (i < nb) ? bsum[i] : 0;
        sm[threadIdx.x] = v;
        __syncthreads();
        #pragma unroll
        for (int off = 1; off < 256; off <<= 1) {
            int t = ((int)threadIdx.x >= off) ? sm[threadIdx.x - off] : 0;
            __syncthreads();
            sm[threadIdx.x] += t;
            __syncthreads();
        }
        if (i < nb) bsum[i] = running + sm[threadIdx.x] - v;   // exclusive
        __syncthreads();
        if (threadIdx.x == 0) running += sm[255];
        __syncthreads();
    }
}

__global__ void scan_final_kernel(const int* __restrict__ incl, const int* __restrict__ bsum,
                                  int* __restrict__ rowptr, int* __restrict__ cursor, int N) {
    int i = blockIdx.x * 256 + threadIdx.x;
    if (i < N) { rowptr[i + 1] = incl[i] + bsum[blockIdx.x]; cursor[i] = 0; }
    if (i == 0) rowptr[0] = 0;
}

// ---------------------------------------------------------------------------
// Scatter edges into CSR order (sorted by dst). cursor zeroed by scan_final.
__global__ void scatter_kernel(const int* __restrict__ ei,
                               const int* __restrict__ rowptr, int* __restrict__ cursor,
                               int* __restrict__ srcs, int E, int E2) {
    int is64 = detect64(ei);
    for (int e = blockIdx.x * blockDim.x + threadIdx.x; e < E2;
         e += gridDim.x * blockDim.x) {
        int s, d;
        if (e < E) {
            if (is64) { s = ei[2 * e]; d = ei[2 * (E + e)]; }
            else      { s = ei[e];     d = ei[E + e]; }
        } else {
            s = d = e - E;
        }
        int pos = rowptr[d] + atomicAdd(&cursor[d], 1);
        srcs[pos] = s;
    }
}

// ---------------------------------------------------------------------------
// Dual GEMM, register-tiled: xl = xin@Wl + bl, xr = xin@Wr + br.
// Interleaved output layout [N][192].
template<int DIN>
__global__ __launch_bounds__(192) void gemm2t_kernel(
    const float* __restrict__ xin,
    const float* __restrict__ Wl, const float* __restrict__ bl,
    const float* __restrict__ Wr, const float* __restrict__ br,
    float* __restrict__ xl, float* __restrict__ xr, int N) {
    int t  = (int)threadIdx.x;
    int cg = t % 48;           // column group -> cols c0..c0+3
    int ng = t / 48;           // node group 0..3
    int c0 = cg * 4;
    int n0 = blockIdx.x * 16 + ng * 4;
    if (n0 >= N) return;

    f4 bLv = *(const f4*)&bl[c0];
    f4 bRv = *(const f4*)&br[c0];
    f4 accL[4], accR[4];
    #pragma unroll
    for (int i = 0; i < 4; ++i) { accL[i] = bLv; accR[i] = bRv; }

    if (n0 + 3 < N) {
        if (DIN == 3) {
            float xv[4][3];
            #pragma unroll
            for (int i = 0; i < 4; ++i) {
                const float* xp = xin + (size_t)(n0 + i) * 3;
                xv[i][0] = xp[0]; xv[i][1] = xp[1]; xv[i][2] = xp[2];
            }
            #pragma unroll
            for (int k = 0; k < 3; ++k) {
                f4 wl4 = *(const f4*)&Wl[k * FDIM + c0];
                f4 wr4 = *(const f4*)&Wr[k * FDIM + c0];
                #pragma unroll
                for (int i = 0; i < 4; ++i) {
                    float xs = xv[i][k];
                    accL[i] += xs * wl4;
                    accR[i] += xs * wr4;
                }
            }
        } else {
            #pragma unroll
            for (int kk = 0; kk < DIN; kk += 8) {
                float xv[4][8];
                #pragma unroll
                for (int i = 0; i < 4; ++i) {
                    const float* xp = xin + (size_t)(n0 + i) * DIN + kk;
                    f4 xa = *(const f4*)xp;
                    f4 xb = *(const f4*)(xp + 4);
                    #pragma unroll
                    for (int q = 0; q < 4; ++q) { xv[i][q] = xa[q]; xv[i][4 + q] = xb[q]; }
                }
                #pragma unroll
                for (int k = 0; k < 8; ++k) {
                    f4 wl4 = *(const f4*)&Wl[(kk + k) * FDIM + c0];
                    f4 wr4 = *(const f4*)&Wr[(kk + k) * FDIM + c0];
                    #pragma unroll
                    for (int i = 0; i < 4; ++i) {
                        float xs = xv[i][k];
                        accL[i] += xs * wl4;
                        accR[i] += xs * wr4;
                    }
                }
            }
        }
        #pragma unroll
        for (int i = 0; i < 4; ++i) {
            *(f4*)&xl[(size_t)(n0 + i) * FDIM + c0] = accL[i];
            *(f4*)&xr[(size_t)(n0 + i) * FDIM + c0] = accR[i];
        }
    } else {
        for (int i = 0; i < 4; ++i) {
            int n = n0 + i;
            if (n >= N) break;
            f4 aL = bLv;
            f4 aR = bRv;
            for (int k = 0; k < DIN; ++k) {
                float xs = xin[(size_t)n * DIN + k];
                f4 wl4 = *(const f4*)&Wl[k * FDIM + c0];
                f4 wr4 = *(const f4*)&Wr[k * FDIM + c0];
                aL += xs * wl4;
                aR += xs * wr4;
            }
            *(f4*)&xl[(size_t)n * FDIM + c0] = aL;
            *(f4*)&xr[(size_t)n * FDIM + c0] = aR;
        }
    }
}

// ---------------------------------------------------------------------------
// Merged GATv2 layer: one wave per destination node (all 4 heads).
// lane -> head h = lane>>4, channel cl = lane&15; owns channels cl, cl+16, cl+32.
// 4-edge batches with clamped indices; defer-max softmax (THR=8): rescale only
// when a batch max exceeds m+8 (wave-uniform __any branch, ~once per node).
#define SCORE_MASKED (-1e38f)
#define M_INIT       (-3e38f)
#define DEFER_THR    8.0f

__global__ __launch_bounds__(256) void gat_layer_kernel(
    const float* __restrict__ xl, const float* __restrict__ xr,
    const float* __restrict__ att, const float* __restrict__ bias,
    const int* __restrict__ rowptr, const int* __restrict__ srcs,
    float* __restrict__ xout,                       // [N,48] (non-final)
    float* __restrict__ out,                        // [N]    (final)
    const float* __restrict__ head_w, const float* __restrict__ head_b,
    int N, int final_flag) {
    int wave = (int)((blockIdx.x * blockDim.x + threadIdx.x) >> 6);
    wave = __builtin_amdgcn_readfirstlane(wave);   // force SGPR: uniform bases
    if (wave >= N) return;
    int lane = (int)(threadIdx.x & 63);
    int n  = wave;
    int h  = lane >> 4;
    int cl = lane & 15;
    int j0 = h * HID + cl;          // flat index into [4*48]

    float a0 = att[j0], a1 = att[j0 + 16], a2 = att[j0 + 32];
    const float* xrp = xr + (size_t)n * FDIM;
    float r0 = xrp[j0], r1 = xrp[j0 + 16], r2 = xrp[j0 + 32];

    float m = M_INIT, denom = 0.f;
    float acc0 = 0.f, acc1 = 0.f, acc2 = 0.f;

    int e0 = rowptr[n], e1 = rowptr[n + 1];
    int elast = e1 - 1;

    for (int e = e0; e < e1; e += 4) {
        int i0 = e,     i1 = e + 1,  i2 = e + 2,  i3 = e + 3;
        int k0 = (i0 < e1) ? i0 : elast;
        int k1 = (i1 < e1) ? i1 : elast;
        int k2 = (i2 < e1) ? i2 : elast;
        int k3 = (i3 < e1) ? i3 : elast;
        int s0 = srcs[k0], s1 = srcs[k1], s2 = srcs[k2], s3 = srcs[k3];
        const float* p0 = xl + (size_t)s0 * FDIM;   // uniform (SGPR) bases
        const float* p1 = xl + (size_t)s1 * FDIM;
        const float* p2 = xl + (size_t)s2 * FDIM;
        const float* p3 = xl + (size_t)s3 * FDIM;
        float l00 = p0[j0], l01 = p0[j0 + 16], l02 = p0[j0 + 32];
        float l10 = p1[j0], l11 = p1[j0 + 16], l12 = p1[j0 + 32];
        float l20 = p2[j0], l21 = p2[j0 + 16], l22 = p2[j0 + 32];
        float l30 = p3[j0], l31 = p3[j0 + 16], l32 = p3[j0 + 32];

        #define LRELU(x) (fmaf(NEG_SLOPE, fminf((x), 0.f), fmaxf((x), 0.f)))
        float sc0 = LRELU(l00 + r0) * a0 + LRELU(l01 + r1) * a1 + LRELU(l02 + r2) * a2;
        float sc1 = LRELU(l10 + r0) * a0 + LRELU(l11 + r1) * a1 + LRELU(l12 + r2) * a2;
        float sc2 = LRELU(l20 + r0) * a0 + LRELU(l21 + r1) * a1 + LRELU(l22 + r2) * a2;
        float sc3 = LRELU(l30 + r0) * a0 + LRELU(l31 + r1) * a1 + LRELU(l32 + r2) * a2;
        #undef LRELU
        sc0 = red16(sc0); sc1 = red16(sc1); sc2 = red16(sc2); sc3 = red16(sc3);
        sc0 = (i0 < e1) ? sc0 : SCORE_MASKED;
        sc1 = (i1 < e1) ? sc1 : SCORE_MASKED;
        sc2 = (i2 < e1) ? sc2 : SCORE_MASKED;
        sc3 = (i3 < e1) ? sc3 : SCORE_MASKED;

        float bmax = fmaxf(fmaxf(sc0, sc1), fmaxf(sc2, sc3));
        if (__any(bmax > m + DEFER_THR)) {          // rare after first batch
            float nm = fmaxf(m, bmax);
            float sc = __expf(m - nm);              // m=M_INIT -> 0
            denom *= sc; acc0 *= sc; acc1 *= sc; acc2 *= sc;
            m = nm;
        }
        float q0 = __expf(sc0 - m);
        float q1 = __expf(sc1 - m);
        float q2 = __expf(sc2 - m);
        float q3 = __expf(sc3 - m);
        denom += (q0 + q1) + (q2 + q3);
        acc0 = fmaf(q0, l00, fmaf(q1, l10, fmaf(q2, l20, fmaf(q3, l30, acc0))));
        acc1 = fmaf(q0, l01, fmaf(q1, l11, fmaf(q2, l21, fmaf(q3, l31, acc1))));
        acc2 = fmaf(q0, l02, fmaf(q1, l12, fmaf(q2, l22, fmaf(q3, l32, acc2))));
    }

    float inv = 1.0f / (denom + 1e-16f);
    float o0 = acc0 * inv, o1 = acc1 * inv, o2 = acc2 * inv;
    // mean over heads: sum across the 4 head groups
    o0 += __shfl_xor(o0, 16); o0 += __shfl_xor(o0, 32);
    o1 += __shfl_xor(o1, 16); o1 += __shfl_xor(o1, 32);
    o2 += __shfl_xor(o2, 16); o2 += __shfl_xor(o2, 32);
    o0 = 0.25f * o0 + bias[cl];
    o1 = 0.25f * o1 + bias[cl + 16];
    o2 = 0.25f * o2 + bias[cl + 32];
    // ELU via exp(x)-1 (fast trans pipe; abs err ~1e-7)
    o0 = (o0 > 0.f) ? o0 : (__expf(o0) - 1.f);
    o1 = (o1 > 0.f) ? o1 : (__expf(o1) - 1.f);
    o2 = (o2 > 0.f) ? o2 : (__expf(o2) - 1.f);

    if (!final_flag) {
        if (h == 0) {
            float* xo = xout + (size_t)n * HID;
            xo[cl] = o0; xo[cl + 16] = o1; xo[cl + 32] = o2;
        }
    } else {
        float part = o0 * head_w[cl] + o1 * head_w[cl + 16] + o2 * head_w[cl + 32];
        part = red16(part);
        if (lane == 0) {
            float v = part + head_b[0];
            out[n] = (v > 0.f) ? v : 0.f;
        }
    }
}

// ---------------------------------------------------------------------------
extern "C" void kernel_launch(void* const* d_in, const int* in_sizes, int n_in,
                              void* d_out, int out_size, void* d_ws, size_t ws_size,
                              hipStream_t stream) {
    const float* x0 = (const float*)d_in[0];
    const int*   ei = (const int*)d_in[1];

    const int N  = in_sizes[0] / 3;        // 50000
    const int E  = in_sizes[1] / 2;        // 800000
    const int E2 = E + N;                  // edges incl. self-loops

    const float* Wl[3];  const float* bl[3];
    const float* Wr[3];  const float* br[3];
    const float* att[3]; const float* bias[3];
    for (int li = 0; li < 3; ++li) {
        int b = 2 + 6 * li;
        Wl[li]   = (const float*)d_in[b + 0];
        bl[li]   = (const float*)d_in[b + 1];
        Wr[li]   = (const float*)d_in[b + 2];
        br[li]   = (const float*)d_in[b + 3];
        att[li]  = (const float*)d_in[b + 4];
        bias[li] = (const float*)d_in[b + 5];
    }
    const float* head_w = (const float*)d_in[20];
    const float* head_b = (const float*)d_in[21];
    float* out = (float*)d_out;

    // ---- workspace carve-up (256B aligned) ----
    size_t off = 0;
    auto alloc = [&](size_t bytes) -> void* {
        void* p = (char*)d_ws + off;
        off = (off + bytes + 255) & ~(size_t)255;
        return p;
    };
    const int nb = (N + 255) / 256;
    int*   deg    = (int*)alloc((size_t)N * sizeof(int));        // reused as cursor
    int*   incl   = (int*)alloc((size_t)N * sizeof(int));
    int*   bsum   = (int*)alloc((size_t)nb * sizeof(int));
    int*   rowptr = (int*)alloc((size_t)(N + 1) * sizeof(int));
    int*   srcs   = (int*)alloc((size_t)E2 * sizeof(int));
    float* xlb    = (float*)alloc((size_t)N * FDIM * sizeof(float));
    float* xrb    = (float*)alloc((size_t)N * FDIM * sizeof(float));
    float* xbuf   = (float*)alloc((size_t)N * HID * sizeof(float));
    (void)ws_size;

    // ---- build CSR (layer-invariant) ----
    (void)hipMemsetAsync(deg, 0, (size_t)N * sizeof(int), stream);
    hist_kernel<<<2048, 256, 0, stream>>>(ei, deg, E, E2);
    scan_local_kernel<<<nb, 256, 0, stream>>>(deg, incl, bsum, N);
    scan_bsum_kernel<<<1, 256, 0, stream>>>(bsum, nb);
    scan_final_kernel<<<nb, 256, 0, stream>>>(incl, bsum, rowptr, deg, N);
    scatter_kernel<<<2048, 256, 0, stream>>>(ei, rowptr, deg, srcs, E, E2);

    const int waves_per_block = 4;  // 256 threads
    int gat_blocks = (N + waves_per_block - 1) / waves_per_block;
    int gemm_blocks = (N + 15) / 16;

    // ---- layer 0 (din=3) ----
    gemm2t_kernel<3><<<gemm_blocks, 192, 0, stream>>>(x0, Wl[0], bl[0], Wr[0], br[0], xlb, xrb, N);
    gat_layer_kernel<<<gat_blocks, 256, 0, stream>>>(xlb, xrb, att[0], bias[0],
        rowptr, srcs, xbuf, nullptr, nullptr, nullptr, N, 0);

    // ---- layer 1 (din=48) ----
    gemm2t_kernel<HID><<<gemm_blocks, 192, 0, stream>>>(xbuf, Wl[1], bl[1], Wr[1], br[1], xlb, xrb, N);
    gat_layer_kernel<<<gat_blocks, 256, 0, stream>>>(xlb, xrb, att[1], bias[1],
        rowptr, srcs, xbuf, nullptr, nullptr, nullptr, N, 0);

    // ---- layer 2 (din=48) + fused head MLP + ReLU ----
    gemm2t_kernel<HID><<<gemm_blocks, 192, 0, stream>>>(xbuf, Wl[2], bl[2], Wr[2], br[2], xlb, xrb, N);
    gat_layer_kernel<<<gat_blocks, 256, 0, stream>>>(xlb, xrb, att[2], bias[2],
        rowptr, srcs, nullptr, out, head_w, head_b, N, 1);

    (void)n_in; (void)out_size;
}